// Round 3
// baseline (708.841 us; speedup 1.0000x reference)
//
#include <hip/hip_runtime.h>

#define HW   262144   // 512*512
#define HW4  65536    // HW/4
#define NSEG 256
#define NB   8

// -------- Kernel 1: accumulate per-(batch,segment) moments ----------------
// acc[b][k][s], k: 0=count, 1..3=Sx_c, 4..6=Sx_c^2, 7=Sx0x1, 8=Sx0x2, 9=Sx1x2
// Direct global fire-and-forget atomics (global_atomic_add_f32, no return):
// LDS DS-atomics with divergent addresses serialize ~3.2cyc/lane (R2 counters);
// L2 atomics are pipelined across channels and don't stall the wave.
__device__ __forceinline__ void accum_px(float* __restrict__ ab, int s,
                                         float x0, float x1, float x2) {
  unsafeAtomicAdd(ab + 0 * NSEG + s, 1.0f);
  unsafeAtomicAdd(ab + 1 * NSEG + s, x0);
  unsafeAtomicAdd(ab + 2 * NSEG + s, x1);
  unsafeAtomicAdd(ab + 3 * NSEG + s, x2);
  unsafeAtomicAdd(ab + 4 * NSEG + s, x0 * x0);
  unsafeAtomicAdd(ab + 5 * NSEG + s, x1 * x1);
  unsafeAtomicAdd(ab + 6 * NSEG + s, x2 * x2);
  unsafeAtomicAdd(ab + 7 * NSEG + s, x0 * x1);
  unsafeAtomicAdd(ab + 8 * NSEG + s, x0 * x2);
  unsafeAtomicAdd(ab + 9 * NSEG + s, x1 * x2);
}

__global__ __launch_bounds__(256) void k_accum(const float* __restrict__ x,
                                               const int* __restrict__ labels,
                                               float* __restrict__ acc) {
  const int t = threadIdx.x;
  const int b = blockIdx.x >> 7;        // 128 blocks per batch
  const int chunk = blockIdx.x & 127;   // 512 float4-groups per block
  const float4* __restrict__ x4 = (const float4*)(x + (size_t)b * 3 * HW);
  const int4*  __restrict__ l4  = (const int4*)(labels + (size_t)b * HW);
  float* __restrict__ ab = acc + b * (10 * NSEG);

  #pragma unroll
  for (int i = 0; i < 2; ++i) {
    const int g = (chunk << 9) + (i << 8) + t;
    float4 a0 = x4[g];
    float4 a1 = x4[HW4 + g];
    float4 a2 = x4[2 * HW4 + g];
    int4  lb  = l4[g];
    accum_px(ab, lb.x, a0.x, a1.x, a2.x);
    accum_px(ab, lb.y, a0.y, a1.y, a2.y);
    accum_px(ab, lb.z, a0.z, a1.z, a2.z);
    accum_px(ab, lb.w, a0.w, a1.w, a2.w);
  }
}

// -------- Kernel 2: moments -> mean/std -> reduce_conv -> L2 normalize ----
// block = 256 threads = 4 waves; each wave handles one (b,s) segment.
__global__ __launch_bounds__(256) void k_stats(const float* __restrict__ acc,
                                               const float* __restrict__ W_pix,
                                               const float* __restrict__ b_pix,
                                               const float* __restrict__ W_red,
                                               const float* __restrict__ b_red,
                                               float* __restrict__ rn) {
  __shared__ float wred[64 * 129];   // +1 pad: bank = (f+g)%32, conflict-free
  __shared__ float comb[4][132];
  const int t = threadIdx.x;

  // stage W_red (64x128) coalesced, padded stride 129
  for (int j4 = t; j4 < 2048; j4 += 256) {
    const int row = j4 >> 5;
    const int c4  = (j4 & 31) << 2;
    float4 v = ((const float4*)W_red)[j4];
    float* d = &wred[row * 129 + c4];
    d[0] = v.x; d[1] = v.y; d[2] = v.z; d[3] = v.w;
  }
  __syncthreads();

  const int w = t >> 6;        // wave in block
  const int f = t & 63;        // feature / lane
  const int seg = blockIdx.x * 4 + w;   // 0..2047
  const int b = seg >> 8;
  const int s = seg & 255;

  const float* a = acc + b * (10 * NSEG);
  const float N   = fmaxf(a[0 * NSEG + s], 1.0f);
  const float S0  = a[1 * NSEG + s];
  const float S1  = a[2 * NSEG + s];
  const float S2  = a[3 * NSEG + s];
  const float M00 = a[4 * NSEG + s];
  const float M11 = a[5 * NSEG + s];
  const float M22 = a[6 * NSEG + s];
  const float M01 = a[7 * NSEG + s];
  const float M02 = a[8 * NSEG + s];
  const float M12 = a[9 * NSEG + s];

  const float w0 = W_pix[f * 3 + 0];
  const float w1 = W_pix[f * 3 + 1];
  const float w2 = W_pix[f * 3 + 2];
  const float bf = b_pix[f];

  const float wS   = w0 * S0 + w1 * S1 + w2 * S2;
  const float mean = (wS + N * bf) / N;
  const float ssq  = w0 * w0 * M00 + w1 * w1 * M11 + w2 * w2 * M22
                   + 2.f * (w0 * w1 * M01 + w0 * w2 * M02 + w1 * w2 * M12)
                   + 2.f * bf * wS + N * bf * bf;
  const float var  = ssq / N - mean * mean;
  const float stdv = sqrtf(fmaxf(var, 1e-6f));

  comb[w][f]      = mean;
  comb[w][64 + f] = stdv;
  __syncthreads();

  float r = b_red[f];
  const float* wr = &wred[f * 129];
  const float* cb = comb[w];
  for (int g = 0; g < 128; ++g) r += wr[g] * cb[g];

  float sq = r * r;
  #pragma unroll
  for (int off = 32; off > 0; off >>= 1) sq += __shfl_xor(sq, off, 64);
  const float inv = 1.0f / fmaxf(sqrtf(sq), 1e-12f);

  rn[(size_t)seg * 64 + f] = r * inv;
}

// -------- Kernel 3: sim = rn rn^T, fused conv1x1 + BN(eval) + ReLU --------
__global__ __launch_bounds__(256) void k_sim(const float* __restrict__ rn,
                                             float* __restrict__ out,
                                             const float* __restrict__ w_sim,
                                             const float* __restrict__ b_sim,
                                             const float* __restrict__ bn_g,
                                             const float* __restrict__ bn_b,
                                             const float* __restrict__ bn_m,
                                             const float* __restrict__ bn_v) {
  __shared__ float A[64 * 65];
  __shared__ float Bt[64 * 65];
  const int t  = threadIdx.x;
  const int b  = blockIdx.x >> 4;
  const int ti = (blockIdx.x >> 2) & 3;
  const int tj = blockIdx.x & 3;

  const float4* rn4 = (const float4*)(rn + (size_t)b * NSEG * 64);
  for (int j4 = t; j4 < 1024; j4 += 256) {
    const int row = j4 >> 4;
    const int c4  = (j4 & 15) << 2;
    float4 va = rn4[(ti * 64 + row) * 16 + (j4 & 15)];
    float* da = &A[row * 65 + c4];
    da[0] = va.x; da[1] = va.y; da[2] = va.z; da[3] = va.w;
    float4 vb = rn4[(tj * 64 + row) * 16 + (j4 & 15)];
    float* db = &Bt[row * 65 + c4];
    db[0] = vb.x; db[1] = vb.y; db[2] = vb.z; db[3] = vb.w;
  }
  __syncthreads();

  const int tx = t & 15;
  const int ty = t >> 4;
  float acc[4][4] = {{0.f}};
  for (int k = 0; k < 64; ++k) {
    float av[4], bv[4];
    #pragma unroll
    for (int i = 0; i < 4; ++i) av[i] = A[(ty * 4 + i) * 65 + k];
    #pragma unroll
    for (int j = 0; j < 4; ++j) bv[j] = Bt[(tx * 4 + j) * 65 + k];
    #pragma unroll
    for (int i = 0; i < 4; ++i)
      #pragma unroll
      for (int j = 0; j < 4; ++j) acc[i][j] += av[i] * bv[j];
  }

  const float invsd = 1.0f / sqrtf(bn_v[0] + 1e-5f);
  const float scale = w_sim[0] * bn_g[0] * invsd;
  const float shift = (b_sim[0] - bn_m[0]) * bn_g[0] * invsd + bn_b[0];

  #pragma unroll
  for (int i = 0; i < 4; ++i) {
    float4 v;
    v.x = fmaxf(acc[i][0] * scale + shift, 0.f);
    v.y = fmaxf(acc[i][1] * scale + shift, 0.f);
    v.z = fmaxf(acc[i][2] * scale + shift, 0.f);
    v.w = fmaxf(acc[i][3] * scale + shift, 0.f);
    const int base = b * 65536 + (ti * 64 + ty * 4 + i) * 256 + tj * 64;
    ((float4*)out)[(base >> 2) + tx] = v;
  }
}

extern "C" void kernel_launch(void* const* d_in, const int* in_sizes, int n_in,
                              void* d_out, int out_size, void* d_ws, size_t ws_size,
                              hipStream_t stream) {
  (void)in_sizes; (void)n_in; (void)out_size; (void)ws_size;
  const float* x      = (const float*)d_in[0];
  const int*   labels = (const int*)d_in[1];
  // d_in[2] = num_spixels (256, hard-coded)
  const float* W_pix  = (const float*)d_in[3];
  const float* b_pix  = (const float*)d_in[4];
  const float* W_red  = (const float*)d_in[5];
  const float* b_red  = (const float*)d_in[6];
  const float* w_sim  = (const float*)d_in[7];
  const float* b_sim  = (const float*)d_in[8];
  const float* bn_g   = (const float*)d_in[9];
  const float* bn_b   = (const float*)d_in[10];
  const float* bn_m   = (const float*)d_in[11];
  const float* bn_v   = (const float*)d_in[12];
  float* out = (float*)d_out;

  float* acc = (float*)d_ws;                       // 8*10*256 floats = 80 KB
  float* rn  = (float*)d_ws + NB * 10 * NSEG;      // 8*256*64 floats = 512 KB

  hipMemsetAsync(acc, 0, NB * 10 * NSEG * sizeof(float), stream);
  k_accum<<<dim3(1024), dim3(256), 0, stream>>>(x, labels, acc);
  k_stats<<<dim3(512), dim3(256), 0, stream>>>(acc, W_pix, b_pix, W_red, b_red, rn);
  k_sim<<<dim3(128), dim3(256), 0, stream>>>(rn, out, w_sim, b_sim, bn_g, bn_b, bn_m, bn_v);
}

// Round 4
// 144.076 us; speedup vs baseline: 4.9199x; 4.9199x over previous
//
#include <hip/hip_runtime.h>

#define HW   262144   // 512*512
#define HW4  65536    // HW/4
#define NSEG 256
#define NB   8

typedef __attribute__((ext_vector_type(4))) float f32x4;
typedef __attribute__((ext_vector_type(8))) short s16x8;

__device__ __forceinline__ unsigned f2bf(float f) {   // fp32 -> bf16 (RNE)
  unsigned u = __float_as_uint(f);
  return (u + 0x7FFFu + ((u >> 16) & 1u)) >> 16;
}

// -------- Kernel 1: per-(batch,segment) moments via MFMA one-hot ----------
// D[m][s] += A[m][k] * B[k][s]; A = 10 moment rows (bf16), B = one-hot(label)
// built in registers. Each wave owns a private LDS region (no barriers in
// the main loop). Block of 4 waves reduces partials in LDS, writes one
// 10x256 fp32 partial per block; k_reduce sums 128 partials per batch.
__global__ __launch_bounds__(256) void k_moments(const float* __restrict__ x,
                                                 const int* __restrict__ labels,
                                                 float* __restrict__ part) {
  __shared__ __align__(16) char smem[4][10240];  // per wave: mom 8KB + lab 1KB (bp 10KB aliases)
  const int t = threadIdx.x, w = t >> 6, lane = t & 63;
  const int b = blockIdx.x >> 7, blk = blockIdx.x & 127;  // 128 blocks/batch
  unsigned short* mom = (unsigned short*)smem[w];          // [16][256] bf16
  int* lab = (int*)(smem[w] + 8192);                       // [256]
  float* bp = (float*)smem[w];                             // [2560] (aliases mom)
  const int q = lane >> 4, n0 = lane & 15;

  // zero A rows 10..15 once (feed D rows we never store; keep them finite)
  #pragma unroll
  for (int m = 10; m < 16; ++m)
    *(uint2*)&mom[m * 256 + 4 * lane] = make_uint2(0u, 0u);

  const float4* __restrict__ x4 = (const float4*)(x + (size_t)b * 3 * HW);
  const int4*  __restrict__ l4  = (const int4*)(labels + (size_t)b * HW);

  f32x4 acc[16];
  #pragma unroll
  for (int i = 0; i < 16; ++i) acc[i] = (f32x4){0.f, 0.f, 0.f, 0.f};

  #pragma unroll
  for (int it = 0; it < 2; ++it) {
    const int g = blk * 512 + w * 128 + it * 64 + lane;   // float4 idx in channel
    float4 a0 = x4[g];
    float4 a1 = x4[HW4 + g];
    float4 a2 = x4[2 * HW4 + g];
    int4  lb  = l4[g];

    float c0[4] = {a0.x, a0.y, a0.z, a0.w};
    float c1[4] = {a1.x, a1.y, a1.z, a1.w};
    float c2[4] = {a2.x, a2.y, a2.z, a2.w};
    float P[10][4];
    #pragma unroll
    for (int k = 0; k < 4; ++k) {
      P[0][k] = 1.f;
      P[1][k] = c0[k];          P[2][k] = c1[k];          P[3][k] = c2[k];
      P[4][k] = c0[k] * c0[k];  P[5][k] = c1[k] * c1[k];  P[6][k] = c2[k] * c2[k];
      P[7][k] = c0[k] * c1[k];  P[8][k] = c0[k] * c2[k];  P[9][k] = c1[k] * c2[k];
    }
    // stage transposed bf16 moments: mom[m][4*lane .. 4*lane+3]
    #pragma unroll
    for (int m = 0; m < 10; ++m) {
      unsigned lo = f2bf(P[m][0]) | (f2bf(P[m][1]) << 16);
      unsigned hi = f2bf(P[m][2]) | (f2bf(P[m][3]) << 16);
      *(uint2*)&mom[m * 256 + 4 * lane] = make_uint2(lo, hi);
    }
    *(int4*)&lab[4 * lane] = lb;

    // 8 K-batches of 32 pixels
    #pragma unroll
    for (int c = 0; c < 8; ++c) {
      s16x8 af = *(s16x8*)&mom[n0 * 256 + c * 32 + q * 8];   // A[m=n0][k=q*8+j]
      int4 lA = *(int4*)&lab[c * 32 + q * 8];
      int4 lB = *(int4*)&lab[c * 32 + q * 8 + 4];
      int lv[8] = {lA.x, lA.y, lA.z, lA.w, lB.x, lB.y, lB.z, lB.w};
      unsigned mk[8];
      #pragma unroll
      for (int j = 0; j < 8; ++j) {
        int d = lv[j] - n0;
        unsigned hit = (((d & 15) == 0) && ((unsigned)d < 256u)) ? 1u : 0u;
        mk[j] = hit << (((unsigned)d >> 4) & 31u);
      }
      unsigned M01 = mk[0] | (mk[1] << 16);
      unsigned M23 = mk[2] | (mk[3] << 16);
      unsigned M45 = mk[4] | (mk[5] << 16);
      unsigned M67 = mk[6] | (mk[7] << 16);
      #pragma unroll
      for (int tl = 0; tl < 16; ++tl) {
        uint4 bi;
        bi.x = ((M01 >> tl) & 0x00010001u) * 0x3F80u;
        bi.y = ((M23 >> tl) & 0x00010001u) * 0x3F80u;
        bi.z = ((M45 >> tl) & 0x00010001u) * 0x3F80u;
        bi.w = ((M67 >> tl) & 0x00010001u) * 0x3F80u;
        s16x8 bf = __builtin_bit_cast(s16x8, bi);
        acc[tl] = __builtin_amdgcn_mfma_f32_16x16x32_bf16(af, bf, acc[tl], 0, 0, 0);
      }
    }
  }

  // scatter D tiles into this wave's bp: D row m=(q*4+r), col s=tl*16+n0
  #pragma unroll
  for (int tl = 0; tl < 16; ++tl)
    #pragma unroll
    for (int r = 0; r < 4; ++r) {
      int m = q * 4 + r;
      if (m < 10) bp[m * 256 + tl * 16 + n0] = acc[tl][r];
    }
  __syncthreads();

  float* o = part + (size_t)blockIdx.x * 2560;
  for (int i = t; i < 2560; i += 256) {
    float s = ((float*)smem[0])[i] + ((float*)smem[1])[i]
            + ((float*)smem[2])[i] + ((float*)smem[3])[i];
    o[i] = s;
  }
}

// -------- Kernel 1b: sum 128 block-partials per batch ---------------------
__global__ __launch_bounds__(256) void k_reduce(const float* __restrict__ part,
                                                float* __restrict__ acc) {
  const int b = blockIdx.x / 10, m = blockIdx.x % 10;
  const float* p = part + (size_t)(b * 128) * 2560 + m * 256 + threadIdx.x;
  float s0 = 0.f, s1 = 0.f, s2 = 0.f, s3 = 0.f;
  for (int i = 0; i < 128; i += 4) {
    s0 += p[(size_t)(i + 0) * 2560];
    s1 += p[(size_t)(i + 1) * 2560];
    s2 += p[(size_t)(i + 2) * 2560];
    s3 += p[(size_t)(i + 3) * 2560];
  }
  acc[(size_t)(b * 10 + m) * 256 + threadIdx.x] = (s0 + s1) + (s2 + s3);
}

// -------- Kernel 2: moments -> mean/std -> reduce_conv -> L2 normalize ----
__global__ __launch_bounds__(256) void k_stats(const float* __restrict__ acc,
                                               const float* __restrict__ W_pix,
                                               const float* __restrict__ b_pix,
                                               const float* __restrict__ W_red,
                                               const float* __restrict__ b_red,
                                               float* __restrict__ rn) {
  __shared__ float wred[64 * 129];
  __shared__ float comb[4][132];
  const int t = threadIdx.x;

  for (int j4 = t; j4 < 2048; j4 += 256) {
    const int row = j4 >> 5;
    const int c4  = (j4 & 31) << 2;
    float4 v = ((const float4*)W_red)[j4];
    float* d = &wred[row * 129 + c4];
    d[0] = v.x; d[1] = v.y; d[2] = v.z; d[3] = v.w;
  }
  __syncthreads();

  const int w = t >> 6;
  const int f = t & 63;
  const int seg = blockIdx.x * 4 + w;
  const int b = seg >> 8;
  const int s = seg & 255;

  const float* a = acc + b * (10 * NSEG);
  const float N   = fmaxf(a[0 * NSEG + s], 1.0f);
  const float S0  = a[1 * NSEG + s];
  const float S1  = a[2 * NSEG + s];
  const float S2  = a[3 * NSEG + s];
  const float M00 = a[4 * NSEG + s];
  const float M11 = a[5 * NSEG + s];
  const float M22 = a[6 * NSEG + s];
  const float M01 = a[7 * NSEG + s];
  const float M02 = a[8 * NSEG + s];
  const float M12 = a[9 * NSEG + s];

  const float w0 = W_pix[f * 3 + 0];
  const float w1 = W_pix[f * 3 + 1];
  const float w2 = W_pix[f * 3 + 2];
  const float bf = b_pix[f];

  const float wS   = w0 * S0 + w1 * S1 + w2 * S2;
  const float mean = (wS + N * bf) / N;
  const float ssq  = w0 * w0 * M00 + w1 * w1 * M11 + w2 * w2 * M22
                   + 2.f * (w0 * w1 * M01 + w0 * w2 * M02 + w1 * w2 * M12)
                   + 2.f * bf * wS + N * bf * bf;
  const float var  = ssq / N - mean * mean;
  const float stdv = sqrtf(fmaxf(var, 1e-6f));

  comb[w][f]      = mean;
  comb[w][64 + f] = stdv;
  __syncthreads();

  float r = b_red[f];
  const float* wr = &wred[f * 129];
  const float* cb = comb[w];
  for (int g = 0; g < 128; ++g) r += wr[g] * cb[g];

  float sq = r * r;
  #pragma unroll
  for (int off = 32; off > 0; off >>= 1) sq += __shfl_xor(sq, off, 64);
  const float inv = 1.0f / fmaxf(sqrtf(sq), 1e-12f);

  rn[(size_t)seg * 64 + f] = r * inv;
}

// -------- Kernel 3: sim = rn rn^T, fused conv1x1 + BN(eval) + ReLU --------
__global__ __launch_bounds__(256) void k_sim(const float* __restrict__ rn,
                                             float* __restrict__ out,
                                             const float* __restrict__ w_sim,
                                             const float* __restrict__ b_sim,
                                             const float* __restrict__ bn_g,
                                             const float* __restrict__ bn_b,
                                             const float* __restrict__ bn_m,
                                             const float* __restrict__ bn_v) {
  __shared__ float A[64 * 65];
  __shared__ float Bt[64 * 65];
  const int t  = threadIdx.x;
  const int b  = blockIdx.x >> 4;
  const int ti = (blockIdx.x >> 2) & 3;
  const int tj = blockIdx.x & 3;

  const float4* rn4 = (const float4*)(rn + (size_t)b * NSEG * 64);
  for (int j4 = t; j4 < 1024; j4 += 256) {
    const int row = j4 >> 4;
    const int c4  = (j4 & 15) << 2;
    float4 va = rn4[(ti * 64 + row) * 16 + (j4 & 15)];
    float* da = &A[row * 65 + c4];
    da[0] = va.x; da[1] = va.y; da[2] = va.z; da[3] = va.w;
    float4 vb = rn4[(tj * 64 + row) * 16 + (j4 & 15)];
    float* db = &Bt[row * 65 + c4];
    db[0] = vb.x; db[1] = vb.y; db[2] = vb.z; db[3] = vb.w;
  }
  __syncthreads();

  const int tx = t & 15;
  const int ty = t >> 4;
  float acc[4][4] = {{0.f}};
  for (int k = 0; k < 64; ++k) {
    float av[4], bv[4];
    #pragma unroll
    for (int i = 0; i < 4; ++i) av[i] = A[(ty * 4 + i) * 65 + k];
    #pragma unroll
    for (int j = 0; j < 4; ++j) bv[j] = Bt[(tx * 4 + j) * 65 + k];
    #pragma unroll
    for (int i = 0; i < 4; ++i)
      #pragma unroll
      for (int j = 0; j < 4; ++j) acc[i][j] += av[i] * bv[j];
  }

  const float invsd = 1.0f / sqrtf(bn_v[0] + 1e-5f);
  const float scale = w_sim[0] * bn_g[0] * invsd;
  const float shift = (b_sim[0] - bn_m[0]) * bn_g[0] * invsd + bn_b[0];

  #pragma unroll
  for (int i = 0; i < 4; ++i) {
    float4 v;
    v.x = fmaxf(acc[i][0] * scale + shift, 0.f);
    v.y = fmaxf(acc[i][1] * scale + shift, 0.f);
    v.z = fmaxf(acc[i][2] * scale + shift, 0.f);
    v.w = fmaxf(acc[i][3] * scale + shift, 0.f);
    const int base = b * 65536 + (ti * 64 + ty * 4 + i) * 256 + tj * 64;
    ((float4*)out)[(base >> 2) + tx] = v;
  }
}

extern "C" void kernel_launch(void* const* d_in, const int* in_sizes, int n_in,
                              void* d_out, int out_size, void* d_ws, size_t ws_size,
                              hipStream_t stream) {
  (void)in_sizes; (void)n_in; (void)out_size; (void)ws_size;
  const float* x      = (const float*)d_in[0];
  const int*   labels = (const int*)d_in[1];
  const float* W_pix  = (const float*)d_in[3];
  const float* b_pix  = (const float*)d_in[4];
  const float* W_red  = (const float*)d_in[5];
  const float* b_red  = (const float*)d_in[6];
  const float* w_sim  = (const float*)d_in[7];
  const float* b_sim  = (const float*)d_in[8];
  const float* bn_g   = (const float*)d_in[9];
  const float* bn_b   = (const float*)d_in[10];
  const float* bn_m   = (const float*)d_in[11];
  const float* bn_v   = (const float*)d_in[12];
  float* out = (float*)d_out;

  float* part = (float*)d_ws;                          // 1024*2560 f32 = 10.5 MB
  float* acc  = part + (size_t)1024 * 2560;            // 8*10*256 = 80 KB
  float* rn   = acc + NB * 10 * NSEG;                  // 8*256*64 = 512 KB

  k_moments<<<dim3(1024), dim3(256), 0, stream>>>(x, labels, part);
  k_reduce<<<dim3(80), dim3(256), 0, stream>>>(part, acc);
  k_stats<<<dim3(512), dim3(256), 0, stream>>>(acc, W_pix, b_pix, W_red, b_red, rn);
  k_sim<<<dim3(128), dim3(256), 0, stream>>>(rn, out, w_sim, b_sim, bn_g, bn_b, bn_m, bn_v);
}